// Round 3
// baseline (216.191 us; speedup 1.0000x reference)
//
#include <hip/hip_runtime.h>

#define T_SZ  16384
#define CIN   8
#define COUT  8
#define NPART 32
#define PART_T 512      // timesteps per part
#define NCH   32        // 16-t chunks per part

struct V3 { float x, y, z; };
__device__ __forceinline__ V3 mkv3(float a, float b, float c) { V3 r; r.x=a; r.y=b; r.z=c; return r; }
__device__ __forceinline__ V3 vadd3(V3 a, V3 b) { return mkv3(a.x+b.x, a.y+b.y, a.z+b.z); }
__device__ __forceinline__ V3 vfma3(V3 acc, float s, V3 w) {
  return mkv3(fmaf(s, w.x, acc.x), fmaf(s, w.y, acc.y), fmaf(s, w.z, acc.z));
}
// A rows: (a0,a1,a2),(0,a1,a2),(0,0,a2)
__device__ __forceinline__ V3 aappf(float a0, float a1, float a2, V3 v) {
  float t2 = a2 * v.z;
  float t1 = fmaf(a1, v.y, t2);
  return mkv3(fmaf(a0, v.x, t1), t1, t2);
}
// combine: E(left|right) = A*E_left + E_right
__device__ __forceinline__ V3 comb(float a0, float a1, float a2, V3 l, V3 r) {
  return vadd3(aappf(a0, a1, a2, l), r);
}

struct Row { float4 lo, hi; };
__device__ __forceinline__ Row ldrow(const float* p) {
  Row r; r.lo = *(const float4*)p; r.hi = *(const float4*)(p + 4); return r;
}
__device__ __forceinline__ Row zrow() { Row r; r.lo = make_float4(0.f,0.f,0.f,0.f); r.hi = r.lo; return r; }
__device__ __forceinline__ float rdot(const Row& r, const float* w) {
  float s = r.lo.x * w[0];
  s = fmaf(r.lo.y, w[1], s); s = fmaf(r.lo.z, w[2], s); s = fmaf(r.lo.w, w[3], s);
  s = fmaf(r.hi.x, w[4], s); s = fmaf(r.hi.y, w[5], s); s = fmaf(r.hi.z, w[6], s);
  s = fmaf(r.hi.w, w[7], s);
  return s;
}

// PHASE 1: per-(b,part) tree roots -> ws.  PHASE 2: full outputs.
// WG = (b, p): 256 threads, thread j -> (c = j>>3: 16-t chunk in part, o = j&7).
template<int PHASE>
__global__ __launch_bounds__(256, 4) void ldtf_pass(
    const float* __restrict__ u, const float* __restrict__ x0,
    const float* __restrict__ ac, const float* __restrict__ bc,
    float* __restrict__ out, float* __restrict__ ws)
{
  __shared__ V3 s_E4[NCH][8];                    // leaf (16-t block) states per channel
  __shared__ V3 s_tr[30][8];                     // in-part tree: b1:0..15 b2:16..23 b3:24..27 b4:28..29
  __shared__ V3 s_mt[(PHASE == 2 ? 62 : 1)][8];  // part-root mini-tree: l0:0..31 l1:32..47 l2:48..55 l3:56..59 l4:60..61

  const int j = threadIdx.x;
  const int o = j & 7;
  const int c = j >> 3;
  const int p = blockIdx.x & 31;
  const int b = blockIdx.x >> 5;

  const float a0 = ac[0*COUT + o];
  const float a1 = ac[1*COUT + o];
  const float a2 = ac[2*COUT + o];

  float w0[8], w1[8], w2[8], w3[8];
#pragma unroll
  for (int i = 0; i < 8; ++i) {
    w0[i] = bc[(0*CIN + i)*COUT + o];
    w1[i] = bc[(1*CIN + i)*COUT + o];
    w2[i] = bc[(2*CIN + i)*COUT + o];
    w3[i] = bc[(3*CIN + i)*COUT + o];
  }

  const float* ub = u + (size_t)b * T_SZ * CIN;
  float* ob = out + (size_t)b * T_SZ * COUT + o;
  const int t0 = p * PART_T + c * 16;

  // ---- FIR into registers ----
  float bv[16];
  {
    Row ra, rb, rc;
    if (t0 == 0) { ra = zrow(); rb = zrow(); rc = zrow(); }
    else {
      ra = ldrow(ub + (size_t)(t0 - 3) * CIN);
      rb = ldrow(ub + (size_t)(t0 - 2) * CIN);
      rc = ldrow(ub + (size_t)(t0 - 1) * CIN);
    }
#pragma unroll
    for (int r = 0; r < 16; ++r) {
      Row rd = ldrow(ub + (size_t)(t0 + r) * CIN);
      bv[r] = rdot(ra, w0) + rdot(rb, w1) + rdot(rc, w2) + rdot(rd, w3);
      ra = rb; rb = rc; rc = rd;
    }
  }

  // ---- specials for global t=0,1 (part 0, chunk 0 only) ----
  V3 e0 = mkv3(0,0,0), e1 = mkv3(0,0,0);
  if (t0 == 0) {
    float x00 = x0[((size_t)b*3 + 0)*COUT + o];
    float x01 = x0[((size_t)b*3 + 1)*COUT + o];
    float x02 = x0[((size_t)b*3 + 2)*COUT + o];
    float first = bv[0] + a2*x00 + a1*x01 + a0*x02;
    e0 = mkv3(first, x02, x01);
    e1 = mkv3(bv[1], bv[1], x02);
  }

  // ---- leaf E4 = sum_r A^(4-popc(r)) e[r] ----
  V3 gt1 = aappf(a0,a1,a2, mkv3(1.f,1.f,1.f));
  V3 gt2 = aappf(a0,a1,a2, gt1);
  V3 gt3 = aappf(a0,a1,a2, gt2);
  V3 gt4 = aappf(a0,a1,a2, gt3);
  {
    V3 gt[5] = { mkv3(1.f,1.f,1.f), gt1, gt2, gt3, gt4 };
    V3 acc;
    if (t0 == 0) {
      V3 p0 = aappf(a0,a1,a2, aappf(a0,a1,a2, aappf(a0,a1,a2, aappf(a0,a1,a2, e0))));
      V3 p1 = aappf(a0,a1,a2, aappf(a0,a1,a2, aappf(a0,a1,a2, e1)));
      acc = vadd3(p0, p1);
#pragma unroll
      for (int r = 2; r < 16; ++r) acc = vfma3(acc, bv[r], gt[4 - __popc(r)]);
    } else {
      acc = mkv3(0,0,0);
#pragma unroll
      for (int r = 0; r < 16; ++r) acc = vfma3(acc, bv[r], gt[4 - __popc(r)]);
    }
    s_E4[c][o] = acc;
  }
  if (PHASE == 2) {
    // cooperative load of the 32 part roots for (b, *, o)
    const float* wp = ws + ((size_t)(b*NPART + c)*8 + o)*3;
    s_mt[c][o] = mkv3(wp[0], wp[1], wp[2]);
  }
  __syncthreads();

  // ---- up-sweep (in-part tree) interleaved with mini-tree build ----
  if (j < 128) { int i = j >> 3; s_tr[i][o] = comb(a0,a1,a2, s_E4[2*i][o], s_E4[2*i+1][o]); }
  __syncthreads();
  if (j < 64)  { int i = j >> 3; s_tr[16+i][o] = comb(a0,a1,a2, s_tr[2*i][o], s_tr[2*i+1][o]); }
  else if (PHASE == 2 && j >= 128) { int i = (j-128) >> 3; s_mt[32+i][o] = comb(a0,a1,a2, s_mt[2*i][o], s_mt[2*i+1][o]); }
  __syncthreads();
  if (j < 32)  { int i = j >> 3; s_tr[24+i][o] = comb(a0,a1,a2, s_tr[16+2*i][o], s_tr[16+2*i+1][o]); }
  else if (PHASE == 2 && j >= 64 && j < 128) { int i = (j-64) >> 3; s_mt[48+i][o] = comb(a0,a1,a2, s_mt[32+2*i][o], s_mt[32+2*i+1][o]); }
  __syncthreads();
  if (j < 16)  { int i = j >> 3; s_tr[28+i][o] = comb(a0,a1,a2, s_tr[24+2*i][o], s_tr[24+2*i+1][o]); }
  else if (PHASE == 2 && j >= 32 && j < 64) { int i = (j-32) >> 3; s_mt[56+i][o] = comb(a0,a1,a2, s_mt[48+2*i][o], s_mt[48+2*i+1][o]); }
  __syncthreads();

  if (PHASE == 1) {
    if (j < 8) {   // part root = comb of the two beta=4 nodes
      V3 rt = comb(a0,a1,a2, s_tr[28][o], s_tr[29][o]);
      float* wp = ws + ((size_t)(b*NPART + p)*8 + o)*3;
      wp[0] = rt.x; wp[1] = rt.y; wp[2] = rt.z;
    }
    return;
  }

  if (j >= 16 && j < 32) { int i = (j-16) >> 3; s_mt[60+i][o] = comb(a0,a1,a2, s_mt[56+2*i][o], s_mt[56+2*i+1][o]); }
  __syncthreads();

  // ---- sigma = rho(t0 - 1): fold Fenwick chain of t0 = p*512 + c*16, high -> low ----
  V3 sig = mkv3(0,0,0);
  if ((p >> 4) & 1) sig = comb(a0,a1,a2, sig, s_mt[60 + (p>>4) - 1][o]);
  if ((p >> 3) & 1) sig = comb(a0,a1,a2, sig, s_mt[56 + (p>>3) - 1][o]);
  if ((p >> 2) & 1) sig = comb(a0,a1,a2, sig, s_mt[48 + (p>>2) - 1][o]);
  if ((p >> 1) & 1) sig = comb(a0,a1,a2, sig, s_mt[32 + (p>>1) - 1][o]);
  if (p & 1)        sig = comb(a0,a1,a2, sig, s_mt[p - 1][o]);
  if ((c >> 4) & 1) sig = comb(a0,a1,a2, sig, s_tr[28 + (c>>4) - 1][o]);
  if ((c >> 3) & 1) sig = comb(a0,a1,a2, sig, s_tr[24 + (c>>3) - 1][o]);
  if ((c >> 2) & 1) sig = comb(a0,a1,a2, sig, s_tr[16 + (c>>2) - 1][o]);
  if ((c >> 1) & 1) sig = comb(a0,a1,a2, sig, s_tr[(c>>1) - 1][o]);
  if (c & 1)        sig = comb(a0,a1,a2, sig, s_E4[c - 1][o]);

  if (t0 > 0) ob[(size_t)(t0 - 1) * COUT] = sig.x;
  if (p == NPART - 1 && c == 1) {   // global root -> out[T-1]
    V3 rt = comb(a0,a1,a2, s_mt[60][o], s_mt[61][o]);
    ob[(size_t)(T_SZ - 1) * COUT] = rt.x;
  }

  // ---- local binary-counter scan: outputs t0 .. t0+14 ----
  {
    V3 st[5];
#pragma unroll
    for (int r = 0; r < 16; ++r) {
      V3 v = mkv3(bv[r], bv[r], bv[r]);
      if (t0 == 0) { if (r == 0) v = e0; if (r == 1) v = e1; }
      if (r & 1)          v = comb(a0,a1,a2, st[0], v);
      if ((r & 3) == 3)   v = comb(a0,a1,a2, st[1], v);
      if ((r & 7) == 7)   v = comb(a0,a1,a2, st[2], v);
      if ((r & 15) == 15) v = comb(a0,a1,a2, st[3], v);
      const int lvl = (r & 1) ? (((r & 3) == 3) ? (((r & 7) == 7) ? (((r & 15) == 15) ? 4 : 3) : 2) : 1) : 0;
      st[lvl] = v;
      if (r < 15) {
        const int i = r + 1;
        V3 acc2 = sig;
        if (i & 8) acc2 = comb(a0,a1,a2, acc2, st[3]);
        if (i & 4) acc2 = comb(a0,a1,a2, acc2, st[2]);
        if (i & 2) acc2 = comb(a0,a1,a2, acc2, st[1]);
        if (i & 1) acc2 = comb(a0,a1,a2, acc2, st[0]);
        ob[(size_t)(t0 + r) * COUT] = acc2.x;
      }
    }
  }
}

extern "C" void kernel_launch(void* const* d_in, const int* in_sizes, int n_in,
                              void* d_out, int out_size, void* d_ws, size_t ws_size,
                              hipStream_t stream) {
  const float* u  = (const float*)d_in[0];
  const float* x0 = (const float*)d_in[1];
  const float* ac = (const float*)d_in[2];
  const float* bc = (const float*)d_in[3];
  float* out = (float*)d_out;
  float* ws  = (float*)d_ws;
  (void)ws_size; (void)in_sizes; (void)n_in; (void)out_size;
  const int grid = 64 * NPART;   // (b, part)
  ldtf_pass<1><<<dim3(grid), dim3(256), 0, stream>>>(u, x0, ac, bc, out, ws);
  ldtf_pass<2><<<dim3(grid), dim3(256), 0, stream>>>(u, x0, ac, bc, out, ws);
}